// Round 5
// baseline (597.092 us; speedup 1.0000x reference)
//
#include <hip/hip_runtime.h>
#include <hip/hip_bf16.h>
#include <stdint.h>

#define M_BATCH 1024
#define N_OUT   4096
#define K_IN    4096

#define BM 128
#define BN 128
#define KPER   2048       // per intra-block k-half
#define BK2    32         // k-elems per half per slab
#define NSLAB  64         // gemm k-slabs
#define NCHUNK 16         // produce chunks (4 slabs = 128 cols per half each)
#define NFLAG  8          // 1 flag per 2 chunks (8 slabs)

typedef __attribute__((ext_vector_type(8))) __bf16 bf16x8_t;
typedef __attribute__((ext_vector_type(4))) float f32x4_t;
typedef __attribute__((ext_vector_type(4))) float fvec4;
typedef __attribute__((ext_vector_type(4))) unsigned short us4_t;

__device__ __forceinline__ unsigned short f2bf_bits(float f) {
    union { __hip_bfloat16 h; unsigned short u; } cvt;
    cvt.h = __float2bfloat16(f);  // RNE
    return cvt.u;
}

// R5: FUSED producer-consumer kernel. 256 blocks x 512 threads, 1 block/CU
// (128 KB LDS forces it; grid == CU count => all blocks co-resident).
// Each block: (a) converts 16 W-rows + 4 x-rows to bf16, k-chunk-major
// (16 chunks x 128 cols per half), NT loads (R0: required, L2 bypass) +
// plain stores (R3: NT stores evicted past MALL); (b) runs the R4 gemm
// (128x128 tile, depth-3 slab pipeline, counted vmcnt) gated on device-scope
// ready-flags so STAGE never reads unproduced data. Produce loads are issued
// at cycle start and stay in flight across the gemm iters (vmcnt(8) leaves
// exactly the 8 newest = the produce loads) -> HBM/MALL BW is consumed
// concurrently with MFMA/LDS work instead of serializing (R4: 55+46 us).
// Coherence: producer fence(release,"agent") (vmcnt drain + buffer_wbl2)
// before each flag atomicAdd publishes stores to the MALL; consumers
// first-touch those lines only after the gate (no stale-line hazard, no
// consumer-side invalidate -> XCD L2 reuse of B-panels preserved).
__global__ __launch_bounds__(512, 2) void fused_kernel(
    const float* __restrict__ x,
    const float* __restrict__ wmu,
    const float* __restrict__ wsig,
    const float* __restrict__ epsw,
    const float* __restrict__ bmu,
    const float* __restrict__ bsig,
    const float* __restrict__ ebias,
    unsigned short* __restrict__ wb,   // [N][K] bf16 (A-side: xb; B-side: wb)
    unsigned short* __restrict__ xb,   // [M][K] bf16
    unsigned int*   __restrict__ ready,
    float* __restrict__ C)
{
    // 4 LDS buffers x 16384 elems (32 KB): per buffer A=[half:2][row:128][ch:4]
    // chunks of 16B at elems [0,8192), B same at [8192,16384).
    __shared__ unsigned short lds[4 * 16384];

    const int t   = threadIdx.x;
    const int b   = blockIdx.x;
    const int bn  = (b & 7) | (((b >> 3) & 3) << 3);   // XCD-aware decode
    const int bm  = b >> 5;
    const int bm0 = bm * BM;
    const int bn0 = bn * BN;
    const int lane  = t & 63;
    const int wave  = t >> 6;
    const int khalf = wave >> 2;
    const int quadw = wave & 3;
    const int wrow  = (quadw >> 1) * 64;
    const int wcol  = (quadw & 1) * 64;
    const int lm    = lane & 15;
    const int quad  = lane >> 4;
    const int fq    = quad ^ ((lm >> 1) & 3);   // de-swizzled phys chunk

    f32x4_t acc[4][4] = {};

    // ---- produce state: block b owns W rows [16b,16b+16), x rows [4b,4b+4).
    const int prow  = b * 16 + (t >> 5);        // W row
    const int pxrow = b * 4 + (t >> 7);         // x row
    fvec4 pm[2], ps[2], pe[2];
    float px[2];

    auto PRODUCE_LOAD = [&](int cc) {
        #pragma unroll
        for (int h = 0; h < 2; ++h) {
            const size_t wo = (size_t)prow * K_IN + h * KPER + cc * 128 + ((t & 31) << 2);
            pm[h] = __builtin_nontemporal_load((const fvec4*)(wmu  + wo));
            ps[h] = __builtin_nontemporal_load((const fvec4*)(wsig + wo));
            pe[h] = __builtin_nontemporal_load((const fvec4*)(epsw + wo));
            const size_t xo = (size_t)pxrow * K_IN + h * KPER + cc * 128 + (t & 127);
            px[h] = __builtin_nontemporal_load(x + xo);
        }
    };
    auto CONVERT_STORE = [&](int cc) {
        #pragma unroll
        for (int h = 0; h < 2; ++h) {
            us4_t o;
            o.x = f2bf_bits(fmaf(pe[h].x, ps[h].x, pm[h].x));
            o.y = f2bf_bits(fmaf(pe[h].y, ps[h].y, pm[h].y));
            o.z = f2bf_bits(fmaf(pe[h].z, ps[h].z, pm[h].z));
            o.w = f2bf_bits(fmaf(pe[h].w, ps[h].w, pm[h].w));
            *(us4_t*)(wb + (size_t)prow * K_IN + h * KPER + cc * 128 + ((t & 31) << 2)) = o;
            xb[(size_t)pxrow * K_IN + h * KPER + cc * 128 + (t & 127)] = f2bf_bits(px[h]);
        }
    };
    auto POLL = [&](int f) {
        if (t == 0) {
            while (__hip_atomic_load(&ready[f], __ATOMIC_RELAXED,
                                     __HIP_MEMORY_SCOPE_AGENT) < 256u)
                __builtin_amdgcn_s_sleep(2);
        }
    };

    // ---- gemm staging sources (R4-verified layout + chunk swizzle).
    const int grow  = t >> 2;                     // 0..127
    const int chlog = (t & 3) ^ ((t >> 3) & 3);
    const unsigned short* srcs[4];
    srcs[0] = xb + (size_t)(bm0 + grow) * K_IN + chlog * 8;   // A half0
    srcs[1] = srcs[0] + KPER;                                  // A half1
    srcs[2] = wb + (size_t)(bn0 + grow) * K_IN + chlog * 8;   // B half0
    srcs[3] = srcs[2] + KPER;                                  // B half1
    char* dstt = (char*)lds + t * 16;

    auto STAGE = [&](int s) {
        const int koff = s * BK2;
        char* d = dstt + (s & 3) * 32768;
        #pragma unroll
        for (int q = 0; q < 4; ++q)
            __builtin_amdgcn_global_load_lds(
                (const __attribute__((address_space(1))) void*)(srcs[q] + koff),
                (__attribute__((address_space(3))) void*)(d + q * 8192), 16, 0, 0);
    };
    auto COMPUTE = [&](int s) {
        const unsigned short* Lb = lds + (s & 3) * 16384;
        const unsigned short* Ah = Lb + khalf * 4096 + (wrow + lm) * 32 + fq * 8;
        const unsigned short* Bh = Lb + 8192 + khalf * 4096 + (wcol + lm) * 32 + fq * 8;
        bf16x8_t a_frag[4], b_frag[4];
        #pragma unroll
        for (int im = 0; im < 4; im++)
            a_frag[im] = *(const bf16x8_t*)(Ah + im * 512);
        #pragma unroll
        for (int jn = 0; jn < 4; jn++)
            b_frag[jn] = *(const bf16x8_t*)(Bh + jn * 512);
        #pragma unroll
        for (int im = 0; im < 4; im++)
            #pragma unroll
            for (int jn = 0; jn < 4; jn++)
                acc[im][jn] = __builtin_amdgcn_mfma_f32_16x16x32_bf16(
                    a_frag[im], b_frag[jn], acc[im][jn], 0, 0, 0);
        __builtin_amdgcn_sched_barrier(0);
    };

    // ---- fused schedule: 19 cycles. Produce chunk c (c<=15); gemm group
    // c-3 (c>=3): 4 slab-iters. Flags: flag G = chunks {2G,2G+1}, signaled
    // at odd c (fence between iters 1,2; atomicAdd after iter-2 barrier).
    PRODUCE_LOAD(0);

    for (int c = 0; c < 19; ++c) {
        if (c < NCHUNK) {
            CONVERT_STORE(c);                 // compiler-inserted vmcnt waits P(c)
            if (c + 1 < NCHUNK) PRODUCE_LOAD(c + 1);
        }
        if (c < 3) {
            if (c == 1) {                     // signal flag 0 (chunks 0,1)
                asm volatile("s_waitcnt vmcnt(0)" ::: "memory");
                __builtin_amdgcn_fence(__ATOMIC_RELEASE, "agent");
                __builtin_amdgcn_s_barrier();
                if (t == 0)
                    __hip_atomic_fetch_add(&ready[0], 1u, __ATOMIC_RELAXED,
                                           __HIP_MEMORY_SCOPE_AGENT);
            }
            continue;
        }
        const int s0 = (c - 3) * 4;
        if (c == 3) {                         // prologue: gate group 0, stage 0-2
            POLL(0);
            __builtin_amdgcn_s_barrier();
            STAGE(0); STAGE(1); STAGE(2);
        } else if (c <= 16) {
            POLL((4 * c - 6) >> 3);           // covers all stages this cycle
        }
        // iter 0
        asm volatile("s_waitcnt vmcnt(8)" ::: "memory");
        __builtin_amdgcn_s_barrier();
        if (s0 + 3 < NSLAB) STAGE(s0 + 3);
        COMPUTE(s0 + 0);
        // iter 1
        asm volatile("s_waitcnt vmcnt(8)" ::: "memory");
        __builtin_amdgcn_s_barrier();
        if (s0 + 4 < NSLAB) STAGE(s0 + 4);
        COMPUTE(s0 + 1);
        // release fence on signal cycles (odd c <= 15): publishes S(c-1),S(c)
        const bool sig = (c & 1) && (c <= 15);
        if (sig) {
            asm volatile("s_waitcnt vmcnt(0)" ::: "memory");
            __builtin_amdgcn_fence(__ATOMIC_RELEASE, "agent");
        }
        // iter 2
        if (c == 18) asm volatile("s_waitcnt vmcnt(4)" ::: "memory");
        else         asm volatile("s_waitcnt vmcnt(8)" ::: "memory");
        __builtin_amdgcn_s_barrier();
        if (sig && t == 0)
            __hip_atomic_fetch_add(&ready[c >> 1], 1u, __ATOMIC_RELAXED,
                                   __HIP_MEMORY_SCOPE_AGENT);
        if (s0 + 5 < NSLAB) STAGE(s0 + 5);
        COMPUTE(s0 + 2);
        // iter 3
        if (c == 18) asm volatile("s_waitcnt vmcnt(0)" ::: "memory");
        else         asm volatile("s_waitcnt vmcnt(8)" ::: "memory");
        __builtin_amdgcn_s_barrier();
        if (s0 + 6 < NSLAB) STAGE(s0 + 6);
        COMPUTE(s0 + 3);
    }

    // ---- epilogue: reduce k-halves through LDS (bufs 0-1 region), add bias.
    f32x4_t* red = (f32x4_t*)lds;
    if (wave >= 4) {
        #pragma unroll
        for (int im = 0; im < 4; im++)
            #pragma unroll
            for (int jn = 0; jn < 4; jn++)
                red[quadw * 1024 + (im * 4 + jn) * 64 + lane] = acc[im][jn];
    }
    __syncthreads();
    if (wave < 4) {
        #pragma unroll
        for (int jn = 0; jn < 4; jn++) {
            const int gn = bn0 + wcol + jn * 16 + lm;
            const float bias = bmu[gn] + ebias[gn] * bsig[gn];
            #pragma unroll
            for (int im = 0; im < 4; im++) {
                const f32x4_t part = red[quadw * 1024 + (im * 4 + jn) * 64 + lane];
                const int gm0 = bm0 + wrow + im * 16 + quad * 4;
                #pragma unroll
                for (int r = 0; r < 4; r++)
                    C[(size_t)(gm0 + r) * N_OUT + gn] = acc[im][jn][r] + part[r] + bias;
            }
        }
    }
}

// Insurance path if d_ws is too small for the bf16 staging buffers.
__global__ __launch_bounds__(256) void naive_kernel(
    const float* __restrict__ x, const float* __restrict__ wmu,
    const float* __restrict__ wsig, const float* __restrict__ bmu,
    const float* __restrict__ bsig, const float* __restrict__ epsw,
    const float* __restrict__ epsb, float* __restrict__ out)
{
    const int o = blockIdx.x * blockDim.x + threadIdx.x;
    const int b = blockIdx.y;
    const float4* xr = (const float4*)(x + (size_t)b * K_IN);
    const float4* mr = (const float4*)(wmu + (size_t)o * K_IN);
    const float4* sr = (const float4*)(wsig + (size_t)o * K_IN);
    const float4* er = (const float4*)(epsw + (size_t)o * K_IN);
    float s = 0.f;
    for (int k = 0; k < K_IN / 4; k++) {
        float4 xv = xr[k], m = mr[k], sg = sr[k], e = er[k];
        s += xv.x * fmaf(e.x, sg.x, m.x);
        s += xv.y * fmaf(e.y, sg.y, m.y);
        s += xv.z * fmaf(e.z, sg.z, m.z);
        s += xv.w * fmaf(e.w, sg.w, m.w);
    }
    out[(size_t)b * N_OUT + o] = s + bmu[o] + epsb[o] * bsig[o];
}

extern "C" void kernel_launch(void* const* d_in, const int* in_sizes, int n_in,
                              void* d_out, int out_size, void* d_ws, size_t ws_size,
                              hipStream_t stream)
{
    const float* x    = (const float*)d_in[0];
    const float* wmu  = (const float*)d_in[1];
    const float* wsig = (const float*)d_in[2];
    const float* bmu  = (const float*)d_in[3];
    const float* bsig = (const float*)d_in[4];
    const float* epsw = (const float*)d_in[5];
    const float* epsb = (const float*)d_in[6];
    float* out = (float*)d_out;

    const size_t elems = (size_t)N_OUT * K_IN + (size_t)M_BATCH * K_IN;
    const size_t need  = elems * sizeof(unsigned short) + NFLAG * sizeof(unsigned int);
    if (ws_size >= need) {
        unsigned short* wb = (unsigned short*)d_ws;                  // [N][K] bf16
        unsigned short* xb = wb + (size_t)N_OUT * K_IN;              // [M][K] bf16
        unsigned int* ready = (unsigned int*)(xb + (size_t)M_BATCH * K_IN);
        hipMemsetAsync(ready, 0, NFLAG * sizeof(unsigned int), stream);
        fused_kernel<<<256, 512, 0, stream>>>(x, wmu, wsig, epsw, bmu, bsig,
                                              epsb, wb, xb, ready, out);
    } else {
        dim3 grid(N_OUT / 256, M_BATCH);
        naive_kernel<<<grid, 256, 0, stream>>>(x, wmu, wsig, bmu, bsig, epsw, epsb, out);
    }
}

// Round 6
// 453.781 us; speedup vs baseline: 1.3158x; 1.3158x over previous
//
#include <hip/hip_runtime.h>
#include <hip/hip_bf16.h>
#include <stdint.h>

#define M_BATCH 1024
#define N_OUT   4096
#define K_IN    4096

#define BM 128
#define BN 128
#define KPER   2048       // per intra-block k-half
#define BK2    32         // k-elems per half per slab
#define NSLAB  64         // gemm k-slabs (each covers 32k in BOTH halves)
#define NGRP   16         // flag groups: group h = slabs [4h,4h+4) = k 128/half
#define NFLAGS (32 * NGRP)

typedef __attribute__((ext_vector_type(8))) __bf16 bf16x8_t;
typedef __attribute__((ext_vector_type(4))) float f32x4_t;
typedef __attribute__((ext_vector_type(4))) float fvec4;
typedef __attribute__((ext_vector_type(4))) unsigned short us4_t;
typedef __attribute__((ext_vector_type(8))) unsigned short us8_t;

__device__ __forceinline__ unsigned short f2bf_bits(float f) {
    union { __hip_bfloat16 h; unsigned short u; } cvt;
    cvt.h = __float2bfloat16(f);  // RNE
    return cvt.u;
}

// Tiny kernel: xb = bf16(x). Separate dispatch => the runtime's inter-kernel
// release/acquire guarantees xb visibility to the fused kernel on any XCD.
// NT loads (R0: required) + plain stores (R3: NT stores evict past MALL).
__global__ __launch_bounds__(256) void xprep_kernel(
    const float* __restrict__ x, unsigned short* __restrict__ xb)
{
    const size_t tid = (size_t)blockIdx.x * blockDim.x + threadIdx.x;
    fvec4 v = __builtin_nontemporal_load((const fvec4*)x + tid);
    us4_t o;
    o.x = f2bf_bits(v.x);
    o.y = f2bf_bits(v.y);
    o.z = f2bf_bits(v.z);
    o.w = f2bf_bits(v.w);
    ((us4_t*)xb)[tid] = o;
}

// R6: fused W-produce + GEMM. 256 blocks x 512 threads (1 block/CU, 128 KB LDS).
// GEMM core = R4's verified 128x128 tile, 4x32KB slab buffers, depth-3
// counted-vmcnt pipeline. NEW: wb is produced IN-KERNEL. Block (bm,bn) owns
// W rows [bn0+16*bm, +16); per k-group h (128 k per half) it converts its
// stripe (NT fp32 loads -> bf16 -> plain stores to wb). The 8 same-bn blocks
// (same XCD under the swizzle - perf only) each add 1 to flags[bn][h]; the
// gemm gates each group's STAGE on flags[bn][h]==8.
// R5-killer fixes: (1) flags are 8-block-local, never grid-wide; (2) no
// vmcnt(0) in the loop - produce(g+4) stores issued at group g are provably
// retired (in-order vmcnt, >=13 newer ops) before the wave-0 release fence
// at group g+1 signals them; (3) one release fence per group on ONE wave.
// Produce lead: data-group h produced at g=h-4, fenced+flagged at g=h-3,
// polled at g=h-1 (a=1), staged g=h-1 a=1..3 / g=h a=0, computed at group h.
__global__ __launch_bounds__(512, 2) void fused_kernel(
    const float* __restrict__ wmu,
    const float* __restrict__ wsig,
    const float* __restrict__ epsw,
    const float* __restrict__ bmu,
    const float* __restrict__ bsig,
    const float* __restrict__ ebias,
    unsigned short* __restrict__ wb,   // [N][K] bf16 (produced here)
    const unsigned short* __restrict__ xb,  // [M][K] bf16 (from xprep)
    unsigned int* __restrict__ flags,  // [32][NGRP], zeroed per launch
    float* __restrict__ C)
{
    __shared__ unsigned short lds[4 * 16384];   // 4 x 32 KB slab buffers

    const int t   = threadIdx.x;
    const int b   = blockIdx.x;
    const int bn  = (b & 7) | (((b >> 3) & 3) << 3);   // same-bn => same XCD (perf)
    const int bm  = b >> 5;                             // 0..7 = stripe owner idx
    const int bm0 = bm * BM;
    const int bn0 = bn * BN;
    const int lane  = t & 63;
    const int wave  = t >> 6;
    const int khalf = wave >> 2;
    const int quadw = wave & 3;
    const int wrow  = (quadw >> 1) * 64;
    const int wcol  = (quadw & 1) * 64;
    const int lm    = lane & 15;
    const int quad  = lane >> 4;
    const int fq    = quad ^ ((lm >> 1) & 3);

    f32x4_t acc[4][4] = {};

    // ---- produce: stripe = W rows [bn0+16*bm, +16), thread t covers
    // row bn0+16*bm+(t>>5), half (t>>4)&1, k-local (t&15)*8 (8 contiguous k).
    const int prow = bn0 + (bm << 4) + (t >> 5);
    const int pkh  = (t >> 4) & 1;
    const int pkl  = (t & 15) << 3;
    const size_t pbase = (size_t)prow * K_IN + (size_t)pkh * KPER + pkl;

    auto PRODUCE = [&](int h) {                  // 7 vmem ops
        const size_t off = pbase + h * 128;
        fvec4 m0 = __builtin_nontemporal_load((const fvec4*)(wmu  + off));
        fvec4 m1 = __builtin_nontemporal_load((const fvec4*)(wmu  + off + 4));
        fvec4 s0 = __builtin_nontemporal_load((const fvec4*)(wsig + off));
        fvec4 s1 = __builtin_nontemporal_load((const fvec4*)(wsig + off + 4));
        fvec4 e0 = __builtin_nontemporal_load((const fvec4*)(epsw + off));
        fvec4 e1 = __builtin_nontemporal_load((const fvec4*)(epsw + off + 4));
        us8_t o;
        o[0] = f2bf_bits(fmaf(e0.x, s0.x, m0.x));
        o[1] = f2bf_bits(fmaf(e0.y, s0.y, m0.y));
        o[2] = f2bf_bits(fmaf(e0.z, s0.z, m0.z));
        o[3] = f2bf_bits(fmaf(e0.w, s0.w, m0.w));
        o[4] = f2bf_bits(fmaf(e1.x, s1.x, m1.x));
        o[5] = f2bf_bits(fmaf(e1.y, s1.y, m1.y));
        o[6] = f2bf_bits(fmaf(e1.z, s1.z, m1.z));
        o[7] = f2bf_bits(fmaf(e1.w, s1.w, m1.w));
        *(us8_t*)(wb + off) = o;                 // plain store -> L2 (flushed by fence)
    };

    // ---- gemm staging sources (R4-verified layout + chunk swizzle).
    const int grow  = t >> 2;
    const int chlog = (t & 3) ^ ((t >> 3) & 3);
    const unsigned short* srcs[4];
    srcs[0] = xb + (size_t)(bm0 + grow) * K_IN + chlog * 8;
    srcs[1] = srcs[0] + KPER;
    srcs[2] = wb + (size_t)(bn0 + grow) * K_IN + chlog * 8;
    srcs[3] = srcs[2] + KPER;
    char* dstt = (char*)lds + t * 16;

    auto STAGE = [&](int s) {                    // 4 vmem ops
        const int koff = s * BK2;
        char* d = dstt + (s & 3) * 32768;
        #pragma unroll
        for (int q = 0; q < 4; ++q)
            __builtin_amdgcn_global_load_lds(
                (const __attribute__((address_space(1))) void*)(srcs[q] + koff),
                (__attribute__((address_space(3))) void*)(d + q * 8192), 16, 0, 0);
    };
    auto COMPUTE = [&](int s) {
        const unsigned short* Lb = lds + (s & 3) * 16384;
        const unsigned short* Ah = Lb + khalf * 4096 + (wrow + lm) * 32 + fq * 8;
        const unsigned short* Bh = Lb + 8192 + khalf * 4096 + (wcol + lm) * 32 + fq * 8;
        bf16x8_t a_frag[4], b_frag[4];
        #pragma unroll
        for (int im = 0; im < 4; im++)
            a_frag[im] = *(const bf16x8_t*)(Ah + im * 512);
        #pragma unroll
        for (int jn = 0; jn < 4; jn++)
            b_frag[jn] = *(const bf16x8_t*)(Bh + jn * 512);
        #pragma unroll
        for (int im = 0; im < 4; im++)
            #pragma unroll
            for (int jn = 0; jn < 4; jn++)
                acc[im][jn] = __builtin_amdgcn_mfma_f32_16x16x32_bf16(
                    a_frag[im], b_frag[jn], acc[im][jn], 0, 0, 0);
        __builtin_amdgcn_sched_barrier(0);
    };

    unsigned int* myflags = flags + bn * NGRP;
    auto POLL = [&](int h) {
        if (t == 0) {
            while (__hip_atomic_load(&myflags[h], __ATOMIC_RELAXED,
                                     __HIP_MEMORY_SCOPE_AGENT) < 8u)
                __builtin_amdgcn_s_sleep(2);
        }
    };

    // ---- prologue: produce data-groups 0..3, publish, gate group 0, prime pipe.
    PRODUCE(0); PRODUCE(1); PRODUCE(2); PRODUCE(3);
    __builtin_amdgcn_fence(__ATOMIC_RELEASE, "agent");   // drain + publish stripes
    __builtin_amdgcn_s_barrier();                        // all waves' stripes out
    if (t == 0) {
        #pragma unroll
        for (int h = 0; h < 4; ++h)
            __hip_atomic_fetch_add(&myflags[h], 1u, __ATOMIC_RELAXED,
                                   __HIP_MEMORY_SCOPE_AGENT);
    }
    POLL(0);
    __builtin_amdgcn_s_barrier();
    STAGE(0); STAGE(1); STAGE(2);

    // ---- main loop: 16 groups x 4 slab-iters.
    for (int g = 0; g < NGRP; ++g) {
        const int s0 = g * 4;
        // a = 0
        asm volatile("s_waitcnt vmcnt(8)" ::: "memory");
        __builtin_amdgcn_s_barrier();
        if (g >= 1 && g <= 12) {
            // produce(g+3) stores (issued at g-1) retired: >=13 newer vmem ops
            // have passed each wave's counted waits since. Publish + signal.
            if (wave == 0) __builtin_amdgcn_fence(__ATOMIC_RELEASE, "agent");
            if (t == 0)
                __hip_atomic_fetch_add(&myflags[g + 3], 1u, __ATOMIC_RELAXED,
                                       __HIP_MEMORY_SCOPE_AGENT);
        }
        STAGE(s0 + 3);
        if (g <= 11) PRODUCE(g + 4);
        COMPUTE(s0);
        // a = 1
        if (g <= 11) asm volatile("s_waitcnt vmcnt(12)" ::: "memory");
        else         asm volatile("s_waitcnt vmcnt(8)" ::: "memory");
        if (g < 15) POLL(g + 1);          // gate next group before its STAGEs
        __builtin_amdgcn_s_barrier();
        if (s0 + 4 < NSLAB) STAGE(s0 + 4);
        COMPUTE(s0 + 1);
        // a = 2
        if (g <= 11)      asm volatile("s_waitcnt vmcnt(12)" ::: "memory");
        else if (g == 15) asm volatile("s_waitcnt vmcnt(4)" ::: "memory");
        else              asm volatile("s_waitcnt vmcnt(8)" ::: "memory");
        __builtin_amdgcn_s_barrier();
        if (s0 + 5 < NSLAB) STAGE(s0 + 5);
        COMPUTE(s0 + 2);
        // a = 3
        if (g <= 11)      asm volatile("s_waitcnt vmcnt(12)" ::: "memory");
        else if (g == 15) asm volatile("s_waitcnt vmcnt(0)" ::: "memory");
        else              asm volatile("s_waitcnt vmcnt(8)" ::: "memory");
        __builtin_amdgcn_s_barrier();
        if (s0 + 6 < NSLAB) STAGE(s0 + 6);
        COMPUTE(s0 + 3);
    }

    // ---- epilogue: reduce the two k-halves through LDS, add bias, store once.
    f32x4_t* red = (f32x4_t*)lds;   // buffers 0-1 region; last computes used buf 2/3
    if (wave >= 4) {
        #pragma unroll
        for (int im = 0; im < 4; im++)
            #pragma unroll
            for (int jn = 0; jn < 4; jn++)
                red[quadw * 1024 + (im * 4 + jn) * 64 + lane] = acc[im][jn];
    }
    __syncthreads();
    if (wave < 4) {
        #pragma unroll
        for (int jn = 0; jn < 4; jn++) {
            const int gn = bn0 + wcol + jn * 16 + lm;
            const float bias = bmu[gn] + ebias[gn] * bsig[gn];
            #pragma unroll
            for (int im = 0; im < 4; im++) {
                const f32x4_t part = red[quadw * 1024 + (im * 4 + jn) * 64 + lane];
                const int gm0 = bm0 + wrow + im * 16 + quad * 4;
                #pragma unroll
                for (int r = 0; r < 4; r++)
                    C[(size_t)(gm0 + r) * N_OUT + gn] = acc[im][jn][r] + part[r] + bias;
            }
        }
    }
}

// Insurance path if d_ws is too small for the bf16 staging buffers.
__global__ __launch_bounds__(256) void naive_kernel(
    const float* __restrict__ x, const float* __restrict__ wmu,
    const float* __restrict__ wsig, const float* __restrict__ bmu,
    const float* __restrict__ bsig, const float* __restrict__ epsw,
    const float* __restrict__ epsb, float* __restrict__ out)
{
    const int o = blockIdx.x * blockDim.x + threadIdx.x;
    const int b = blockIdx.y;
    const float4* xr = (const float4*)(x + (size_t)b * K_IN);
    const float4* mr = (const float4*)(wmu + (size_t)o * K_IN);
    const float4* sr = (const float4*)(wsig + (size_t)o * K_IN);
    const float4* er = (const float4*)(epsw + (size_t)o * K_IN);
    float s = 0.f;
    for (int k = 0; k < K_IN / 4; k++) {
        float4 xv = xr[k], m = mr[k], sg = sr[k], e = er[k];
        s += xv.x * fmaf(e.x, sg.x, m.x);
        s += xv.y * fmaf(e.y, sg.y, m.y);
        s += xv.z * fmaf(e.z, sg.z, m.z);
        s += xv.w * fmaf(e.w, sg.w, m.w);
    }
    out[(size_t)b * N_OUT + o] = s + bmu[o] + epsb[o] * bsig[o];
}

extern "C" void kernel_launch(void* const* d_in, const int* in_sizes, int n_in,
                              void* d_out, int out_size, void* d_ws, size_t ws_size,
                              hipStream_t stream)
{
    const float* x    = (const float*)d_in[0];
    const float* wmu  = (const float*)d_in[1];
    const float* wsig = (const float*)d_in[2];
    const float* bmu  = (const float*)d_in[3];
    const float* bsig = (const float*)d_in[4];
    const float* epsw = (const float*)d_in[5];
    const float* epsb = (const float*)d_in[6];
    float* out = (float*)d_out;

    const size_t elems = (size_t)N_OUT * K_IN + (size_t)M_BATCH * K_IN;
    const size_t need  = elems * sizeof(unsigned short) + NFLAGS * sizeof(unsigned int);
    if (ws_size >= need) {
        unsigned short* wb = (unsigned short*)d_ws;                  // [N][K] bf16
        unsigned short* xb = wb + (size_t)N_OUT * K_IN;              // [M][K] bf16
        unsigned int* flags = (unsigned int*)(xb + (size_t)M_BATCH * K_IN);
        hipMemsetAsync(flags, 0, NFLAGS * sizeof(unsigned int), stream);
        xprep_kernel<<<4096, 256, 0, stream>>>(x, xb);
        fused_kernel<<<256, 512, 0, stream>>>(wmu, wsig, epsw, bmu, bsig,
                                              epsb, wb, xb, flags, out);
    } else {
        dim3 grid(N_OUT / 256, M_BATCH);
        naive_kernel<<<grid, 256, 0, stream>>>(x, wmu, wsig, bmu, bsig, epsw, epsb, out);
    }
}

// Round 7
// 270.831 us; speedup vs baseline: 2.2047x; 1.6755x over previous
//
#include <hip/hip_runtime.h>
#include <hip/hip_bf16.h>
#include <stdint.h>

#define M_BATCH 1024
#define N_OUT   4096
#define K_IN    4096

#define BM 128
#define BN 128
#define KSLICE 2048        // K per block (split-K x2)
#define BK3    32          // k per intra-block half per slab
#define KIT3   32          // 1024 / BK3

typedef __attribute__((ext_vector_type(8))) __bf16 bf16x8_t;
typedef __attribute__((ext_vector_type(4))) float f32x4_t;
typedef __attribute__((ext_vector_type(4))) float fvec4;
typedef __attribute__((ext_vector_type(4))) unsigned short us4_t;

__device__ __forceinline__ unsigned short f2bf_bits(float f) {
    union { __hip_bfloat16 h; unsigned short u; } cvt;
    cvt.h = __float2bfloat16(f);  // RNE
    return cvt.u;
}

// Kernel 1: w_bf16 = bf16(mu + eps*sigma); x_bf16 = bf16(x).
// R0-verified config: NT loads (required: plain loads thrash XCD L2s,
// 4.9 -> 3.0 TB/s at constant FETCH_SIZE) + plain stores (required: NT
// stores evict wb/xb past the MALL and gemm re-fetches 42 MB from HBM).
__global__ __launch_bounds__(256) void prep_kernel(
    const float* __restrict__ x,
    const float* __restrict__ wmu,
    const float* __restrict__ wsig,
    const float* __restrict__ epsw,
    unsigned short* __restrict__ wb,
    unsigned short* __restrict__ xb)
{
    const size_t tid = (size_t)blockIdx.x * blockDim.x + threadIdx.x;
    const size_t T   = (size_t)1048576;          // 4096 blocks x 256 threads

    const fvec4* wmu4  = (const fvec4*)wmu;
    const fvec4* wsig4 = (const fvec4*)wsig;
    const fvec4* epsw4 = (const fvec4*)epsw;
    us4_t* wb4 = (us4_t*)wb;

    fvec4 m[4], s[4], e[4];
    #pragma unroll
    for (int r = 0; r < 4; ++r) {
        const size_t i = tid + (size_t)r * T;    // NW4 = 4T exactly
        m[r] = __builtin_nontemporal_load(wmu4  + i);
        s[r] = __builtin_nontemporal_load(wsig4 + i);
        e[r] = __builtin_nontemporal_load(epsw4 + i);
    }
    #pragma unroll
    for (int r = 0; r < 4; ++r) {
        us4_t o;
        o.x = f2bf_bits(fmaf(e[r].x, s[r].x, m[r].x));
        o.y = f2bf_bits(fmaf(e[r].y, s[r].y, m[r].y));
        o.z = f2bf_bits(fmaf(e[r].z, s[r].z, m[r].z));
        o.w = f2bf_bits(fmaf(e[r].w, s[r].w, m[r].w));
        wb4[tid + (size_t)r * T] = o;            // plain store
    }

    fvec4 v = __builtin_nontemporal_load((const fvec4*)x + tid);
    us4_t o;
    o.x = f2bf_bits(v.x);
    o.y = f2bf_bits(v.y);
    o.z = f2bf_bits(v.z);
    o.w = f2bf_bits(v.w);
    ((us4_t*)xb)[tid] = o;                       // plain store
}

// Kernel 2: C += A @ B^T partials, split-K x2 across blocks.
// R6 change: grid 512 = 8 bm x 32 bn x 2 kslice -> TWO blocks per CU
// (64 KB LDS, <=128 VGPR via __launch_bounds__(512,4)). R3/R4 evidence:
// the 16-MFMA-per-barrier structure at 1 block/CU is stalled on the
// barrier drain (MfmaUtil 23.7%, all else low); a second co-resident
// block hides that stall (m97's multi-block mechanism). Each block runs
// the proven structure over K=2048: 8 waves = 2 k-halves (1024 each) x
// 4 quadrants, 2 x 32 KB LDS slab double-buffer (BK=32/half), chunk-XOR
// swizzle pre-applied at the global source, prefetch-after-barrier.
// Epilogue: intra-block k-half reduce through LDS, then BOTH kslice
// blocks unsafeAtomicAdd (native global_atomic_add_f32) partial (+bias
// only on kslice 0) into the pre-zeroed C. The tile pair (b, b+256)
// shares b%8 -> same XCD under round-robin: atomics and wb-panel reads
// stay XCD-local (perf-only heuristic).
__global__ __launch_bounds__(512, 4) void gemm_splitk_kernel(
    const unsigned short* __restrict__ A,
    const unsigned short* __restrict__ B,
    const float* __restrict__ bmu,
    const float* __restrict__ bsig,
    const float* __restrict__ ebias,
    float* __restrict__ C)
{
    // 2 buffers x 16384 elems (32 KB). Per buffer (elems):
    //   A: [half:2][row:128][ch:4]*8 at 0      (8192 elems)
    //   B: same shape at 8192.
    __shared__ unsigned short lds[2 * 16384];

    const int t   = threadIdx.x;
    const int b   = blockIdx.x;
    const int bn  = (b & 7) | (((b >> 3) & 3) << 3);   // 0..31, same-bn => same XCD
    const int bm  = (b >> 5) & 7;                       // 0..7
    const int ks  = b >> 8;                             // 0/1 k-slice
    const int bm0 = bm * BM;
    const int bn0 = bn * BN;
    const int lane  = t & 63;
    const int wave  = t >> 6;
    const int khalf = wave >> 2;          // 0/1: k-half within this block's slice
    const int quadw = wave & 3;
    const int wrow  = (quadw >> 1) * 64;
    const int wcol  = (quadw & 1) * 64;
    const int lm    = lane & 15;
    const int quad  = lane >> 4;
    const int fq    = quad ^ ((lm >> 1) & 3);   // de-swizzled phys chunk

    f32x4_t acc[4][4] = {};

    // Staging: thread t stages 4 chunks/slab: q=0,1 -> A half0/1; q=2,3 -> B.
    // Phys slot (row = t>>2, ch = t&3) holds logical chunk (t&3)^((t>>3)&3).
    const int rlow  = t >> 2;                     // 0..127
    const int chlog = (t & 3) ^ ((t >> 3) & 3);
    const int kb    = ks * KSLICE;
    const unsigned short* srcs[4];
    srcs[0] = A + (size_t)(bm0 + rlow) * K_IN + kb + chlog * 8;
    srcs[1] = srcs[0] + 1024;                     // half 1 of this slice
    srcs[2] = B + (size_t)(bn0 + rlow) * K_IN + kb + chlog * 8;
    srcs[3] = srcs[2] + 1024;
    char* dstt = (char*)lds + t * 16;

    auto STAGE = [&](int s) {
        const int koff = s * BK3;                 // elems within the half
        char* d = dstt + (s & 1) * 32768;
        #pragma unroll
        for (int q = 0; q < 4; ++q)
            __builtin_amdgcn_global_load_lds(
                (const __attribute__((address_space(1))) void*)(srcs[q] + koff),
                (__attribute__((address_space(3))) void*)(d + q * 8192), 16, 0, 0);
    };
    auto COMPUTE = [&](int s) {
        const unsigned short* Lb = lds + (s & 1) * 16384;
        const unsigned short* Ah = Lb + khalf * 4096 + (wrow + lm) * 32 + fq * 8;
        const unsigned short* Bh = Lb + 8192 + khalf * 4096 + (wcol + lm) * 32 + fq * 8;
        bf16x8_t a_frag[4], b_frag[4];
        #pragma unroll
        for (int im = 0; im < 4; im++)
            a_frag[im] = *(const bf16x8_t*)(Ah + im * 512);
        #pragma unroll
        for (int jn = 0; jn < 4; jn++)
            b_frag[jn] = *(const bf16x8_t*)(Bh + jn * 512);
        #pragma unroll
        for (int im = 0; im < 4; im++)
            #pragma unroll
            for (int jn = 0; jn < 4; jn++)
                acc[im][jn] = __builtin_amdgcn_mfma_f32_16x16x32_bf16(
                    a_frag[im], b_frag[jn], acc[im][jn], 0, 0, 0);
        __builtin_amdgcn_sched_barrier(0);
    };

    STAGE(0);
    for (int it = 0; it < KIT3; ++it) {
        __syncthreads();           // buf(it&1) ready; other block hides the drain
        if (it + 1 < KIT3) STAGE(it + 1);
        COMPUTE(it);
    }

    // Epilogue: reduce the two k-halves through LDS (reuses BOTH buffers ->
    // barrier first), then atomic-accumulate into pre-zeroed C.
    __syncthreads();
    f32x4_t* red = (f32x4_t*)lds;   // 4 regions x 1024 f32x4 = 64 KB exactly
    if (wave >= 4) {
        #pragma unroll
        for (int im = 0; im < 4; im++)
            #pragma unroll
            for (int jn = 0; jn < 4; jn++)
                red[quadw * 1024 + (im * 4 + jn) * 64 + lane] = acc[im][jn];
    }
    __syncthreads();
    if (wave < 4) {
        #pragma unroll
        for (int jn = 0; jn < 4; jn++) {
            const int gn = bn0 + wcol + jn * 16 + lm;
            const float bias = (ks == 0) ? (bmu[gn] + ebias[gn] * bsig[gn]) : 0.f;
            #pragma unroll
            for (int im = 0; im < 4; im++) {
                const f32x4_t part = red[quadw * 1024 + (im * 4 + jn) * 64 + lane];
                const int gm0 = bm0 + wrow + im * 16 + quad * 4;
                #pragma unroll
                for (int r = 0; r < 4; r++)
                    unsafeAtomicAdd(&C[(size_t)(gm0 + r) * N_OUT + gn],
                                    acc[im][jn][r] + part[r] + bias);
            }
        }
    }
}

// Insurance path if d_ws is too small for the bf16 staging buffers.
__global__ __launch_bounds__(256) void naive_kernel(
    const float* __restrict__ x, const float* __restrict__ wmu,
    const float* __restrict__ wsig, const float* __restrict__ bmu,
    const float* __restrict__ bsig, const float* __restrict__ epsw,
    const float* __restrict__ epsb, float* __restrict__ out)
{
    const int o = blockIdx.x * blockDim.x + threadIdx.x;
    const int b = blockIdx.y;
    const float4* xr = (const float4*)(x + (size_t)b * K_IN);
    const float4* mr = (const float4*)(wmu + (size_t)o * K_IN);
    const float4* sr = (const float4*)(wsig + (size_t)o * K_IN);
    const float4* er = (const float4*)(epsw + (size_t)o * K_IN);
    float s = 0.f;
    for (int k = 0; k < K_IN / 4; k++) {
        float4 xv = xr[k], m = mr[k], sg = sr[k], e = er[k];
        s += xv.x * fmaf(e.x, sg.x, m.x);
        s += xv.y * fmaf(e.y, sg.y, m.y);
        s += xv.z * fmaf(e.z, sg.z, m.z);
        s += xv.w * fmaf(e.w, sg.w, m.w);
    }
    out[(size_t)b * N_OUT + o] = s + bmu[o] + epsb[o] * bsig[o];
}

extern "C" void kernel_launch(void* const* d_in, const int* in_sizes, int n_in,
                              void* d_out, int out_size, void* d_ws, size_t ws_size,
                              hipStream_t stream)
{
    const float* x    = (const float*)d_in[0];
    const float* wmu  = (const float*)d_in[1];
    const float* wsig = (const float*)d_in[2];
    const float* bmu  = (const float*)d_in[3];
    const float* bsig = (const float*)d_in[4];
    const float* epsw = (const float*)d_in[5];
    const float* epsb = (const float*)d_in[6];
    float* out = (float*)d_out;

    const size_t need = ((size_t)N_OUT * K_IN + (size_t)M_BATCH * K_IN) * sizeof(unsigned short);
    if (ws_size >= need) {
        unsigned short* wb = (unsigned short*)d_ws;                  // [N][K] bf16
        unsigned short* xb = wb + (size_t)N_OUT * K_IN;              // [M][K] bf16
        hipMemsetAsync(out, 0, (size_t)M_BATCH * N_OUT * sizeof(float), stream);
        prep_kernel<<<4096, 256, 0, stream>>>(x, wmu, wsig, epsw, wb, xb);
        gemm_splitk_kernel<<<512, 512, 0, stream>>>(xb, wb, bmu, bsig, epsb, out);
    } else {
        dim3 grid(N_OUT / 256, M_BATCH);
        naive_kernel<<<grid, 256, 0, stream>>>(x, wmu, wsig, bmu, bsig, epsw, epsb, out);
    }
}